// Round 12
// baseline (967.098 us; speedup 1.0000x reference)
//
#include <hip/hip_runtime.h>
#include <hip/hip_bf16.h>
#include <cstdint>

#define SEQ   16384
#define ED    1152
#define NH    16
#define HD    72
#define NSEG  8
#define SEGLEN 2048
#define QKVN  3456
#define NT    (SEGLEN / 64)

typedef __bf16 bf16x8 __attribute__((ext_vector_type(8)));
typedef __bf16 bf16x4 __attribute__((ext_vector_type(4)));
typedef float  f32x4  __attribute__((ext_vector_type(4)));
typedef unsigned int u32x4 __attribute__((ext_vector_type(4)));
typedef __hip_bfloat16 bf16;

__device__ __forceinline__ unsigned short f2bfbits(float f) {
  bf16 h = __float2bfloat16(f);
  return __builtin_bit_cast(unsigned short, h);
}

__device__ __forceinline__ float fexp2(float x) {
#if __has_builtin(__builtin_amdgcn_exp2f)
  return __builtin_amdgcn_exp2f(x);
#else
  return exp2f(x);
#endif
}

// HW packed f32->bf16 convert (RNE); no builtin on gfx950 -> inline asm
__device__ __forceinline__ unsigned int cvt_pk_bf16(float lo, float hi) {
  unsigned int r;
  asm("v_cvt_pk_bf16_f32 %0, %1, %2" : "=v"(r) : "v"(lo), "v"(hi));
  return r;
}

__device__ __forceinline__ void gload_lds16(const void* g, void* l) {
  __builtin_amdgcn_global_load_lds(
      (__attribute__((address_space(1))) void*)(void*)g,
      (__attribute__((address_space(3))) void*)l, 16, 0, 0);
}

// ---------------- prep kernels ----------------
__global__ __launch_bounds__(256) void cvt_f32_bf16(const float* __restrict__ in,
                                                    bf16* __restrict__ out, int n4) {
  int i = blockIdx.x * 256 + threadIdx.x;
  if (i >= n4) return;
  float4 v = reinterpret_cast<const float4*>(in)[i];
  ushort4 o;
  o.x = f2bfbits(v.x); o.y = f2bfbits(v.y); o.z = f2bfbits(v.z); o.w = f2bfbits(v.w);
  reinterpret_cast<ushort4*>(out)[i] = o;
}

// ---------------- GEMM: C[M][N] = A[M][K] * B[N][K]^T + bias, m97-style ----------------
__global__ __launch_bounds__(256) void gemm_bt(const bf16* __restrict__ A,
                                               const bf16* __restrict__ B,
                                               const float* __restrict__ bias,
                                               void* __restrict__ Cout,
                                               int M, int N, int K, int out_bf16) {
  __shared__ __align__(16) bf16 As[128 * 32];
  __shared__ __align__(16) bf16 Bs[128 * 32];
  const int nt   = N >> 7;
  const int bm   = blockIdx.x / nt;
  const int bn   = blockIdx.x % nt;
  const int tid  = threadIdx.x;
  const int lane = tid & 63;
  const int wave = tid >> 6;
  const int wr   = wave >> 1, wc = wave & 1;

  const bf16* Ab = A + (size_t)(bm * 128) * K;
  const bf16* Bb = B + (size_t)(bn * 128) * K;
  const int r0 = tid >> 2;
  const int c0 = (tid & 3) << 3;

  char* AsB = (char*)As;
  char* BsB = (char*)Bs;
  const int ldsoff = wave * 1024;

  const int row15 = lane & 15;
  const int koff  = (lane >> 4) << 3;

  f32x4 acc[4][4] = {};

  for (int k0 = 0; k0 < K; k0 += 32) {
    gload_lds16(Ab + (size_t)r0 * K + k0 + c0,        AsB + ldsoff);
    gload_lds16(Ab + (size_t)(r0 + 64) * K + k0 + c0, AsB + 4096 + ldsoff);
    gload_lds16(Bb + (size_t)r0 * K + k0 + c0,        BsB + ldsoff);
    gload_lds16(Bb + (size_t)(r0 + 64) * K + k0 + c0, BsB + 4096 + ldsoff);
    __syncthreads();
    bf16x8 a[4], b[4];
#pragma unroll
    for (int mi = 0; mi < 4; ++mi)
      a[mi] = *reinterpret_cast<const bf16x8*>(&As[(wr * 64 + mi * 16 + row15) * 32 + koff]);
#pragma unroll
    for (int ni = 0; ni < 4; ++ni)
      b[ni] = *reinterpret_cast<const bf16x8*>(&Bs[(wc * 64 + ni * 16 + row15) * 32 + koff]);
#pragma unroll
    for (int mi = 0; mi < 4; ++mi)
#pragma unroll
      for (int ni = 0; ni < 4; ++ni)
        acc[mi][ni] = __builtin_amdgcn_mfma_f32_16x16x32_bf16(a[mi], b[ni], acc[mi][ni], 0, 0, 0);
    __syncthreads();
  }

  const int crow = bm * 128 + wr * 64 + (lane >> 4) * 4;
  const int ccol = bn * 128 + wc * 64 + row15;
#pragma unroll
  for (int mi = 0; mi < 4; ++mi)
#pragma unroll
    for (int ni = 0; ni < 4; ++ni) {
      const int col = ccol + ni * 16;
      const float bv = bias[col];
#pragma unroll
      for (int r = 0; r < 4; ++r) {
        const int row = crow + mi * 16 + r;
        float v = acc[mi][ni][r] + bv;
        if (out_bf16)
          reinterpret_cast<bf16*>(Cout)[(size_t)row * N + col] = __float2bfloat16(v);
        else
          reinterpret_cast<float*>(Cout)[(size_t)row * N + col] = v;
      }
    }
}

// ---------------- RoPE in-place on qkv [s][3456] ----------------
__global__ __launch_bounds__(256) void rope_inplace(bf16* __restrict__ qkv,
                                                    const float* __restrict__ ang) {
  const int s = blockIdx.x;
  bf16* row = qkv + (size_t)s * QKVN;
  for (int i = threadIdx.x; i < 2 * NH * 36; i += 256) {
    int t   = i / (NH * 36);
    int rem = i - t * (NH * 36);
    int h   = rem / 36;
    int d2  = rem - h * 36;
    float a  = ang[s * 36 + d2];
    float cs = cosf(a), sn = sinf(a);
    bf16* p = row + t * ED + h * HD + d2;
    float x1 = __bfloat162float(p[0]);
    float x2 = __bfloat162float(p[36]);
    p[0]  = __float2bfloat16(x1 * cs - x2 * sn);
    p[36] = __float2bfloat16(x2 * cs + x1 * sn);
  }
}

// ---------------- flash attention v9 ----------------
// v8 + K-prefetch: next tile's 12 K fragments are loaded into registers right after
// the current QK^T consumes them -> L1/L2 latency hides under softmax+stage+barrier+PV.
#define VTSTRIDE (80 * 72)
__global__ __launch_bounds__(256, 3) void attn(const bf16* __restrict__ qkv,
                                               bf16* __restrict__ ctx) {
  const int blk  = blockIdx.x;
  // swizzle: all 16 q-tiles of one (seg,head) land on one XCD for K/V L2 locality
  const int qt   = (blk >> 3) & 15;
  const int g    = (((blk >> 7) & 15) << 3) | (blk & 7);
  const int head = g & 15;
  const int seg  = g >> 4;
  const int q0   = seg * SEGLEN + qt * 128;

  const int tid = threadIdx.x, lane = tid & 63, w = tid >> 6;
  const int row15 = lane & 15, hi = lane >> 4, koff = hi << 3;

  __shared__ __align__(16) bf16 Vt[3 * VTSTRIDE];  // [d][kv] stride 72, chunk-rotated, 3 bufs

  const bf16* Qg = qkv + (size_t)q0 * QKVN + head * HD;
  const bf16* Kg = qkv + (size_t)(seg * SEGLEN) * QKVN + ED + head * HD;
  const bf16* Vg = qkv + (size_t)(seg * SEGLEN) * QKVN + 2 * ED + head * HD;

  // Q fragments (2 q-groups x 3 k-chunks; chunk 2 = cols 64..71, low lanes only)
  const bf16x8 zero8 = {};
  bf16x8 aq[2][3];
#pragma unroll
  for (int m = 0; m < 2; ++m) {
    const bf16* qrow = Qg + (size_t)(w * 32 + m * 16 + row15) * QKVN;
    aq[m][0] = *reinterpret_cast<const bf16x8*>(qrow + koff);
    aq[m][1] = *reinterpret_cast<const bf16x8*>(qrow + 32 + koff);
    aq[m][2] = (hi == 0) ? *reinterpret_cast<const bf16x8*>(qrow + 64) : zero8;
  }

  f32x4 oacc[2][5] = {};
  float lacc[2] = {0.f, 0.f};
  const float c2 = 0.11785113019775793f * 1.4426950408889634f;  // scale * log2(e)

  // stage V tile kt2 into Vt buffer (transpose + column rotation jj=(j+8*(d>>3))&63)
  auto stage_v = [&](int kt2) {
    bf16* dst = Vt + (kt2 % 3) * VTSTRIDE;
    const bf16* src0 = Vg + (size_t)kt2 * 64 * QKVN;
    for (int c = tid; c < 576; c += 256) {
      int j = c / 9, m9 = c - j * 9;
      int d0 = m9 << 3;
      int jj = (j + (m9 << 3)) & 63;
      bf16x8 v = *reinterpret_cast<const bf16x8*>(src0 + (size_t)j * QKVN + d0);
      const unsigned short* u = reinterpret_cast<const unsigned short*>(&v);
#pragma unroll
      for (int e = 0; e < 8; ++e)
        dst[(d0 + e) * 72 + jj] = __builtin_bit_cast(bf16, u[e]);
    }
  };

  // load 12 K fragments of tile kt2 into kr (8 full + 4 tail-on-low-lanes)
  auto load_k = [&](int kt2, bf16x8 (&kr)[12]) {
    const bf16* Kt = Kg + (size_t)kt2 * 64 * QKVN;
#pragma unroll
    for (int ks = 0; ks < 2; ++ks)
#pragma unroll
      for (int kb = 0; kb < 4; ++kb)
        kr[ks * 4 + kb] = *reinterpret_cast<const bf16x8*>(
            Kt + (size_t)(kb * 16 + row15) * QKVN + ks * 32 + koff);
#pragma unroll
    for (int kb = 0; kb < 4; ++kb)
      kr[8 + kb] = (hi == 0) ? *reinterpret_cast<const bf16x8*>(
                                   Kt + (size_t)(kb * 16 + row15) * QKVN + 64)
                             : zero8;
  };

  bf16x8 kreg[12];
  stage_v(0);
  load_k(0, kreg);

  for (int kt = 0; kt < NT; ++kt) {
    // ---- S^T = K Q^T from prefetched kreg ----
    // s[qg][kb][r] = S[q = w*32+qg*16+row15][kv = kb*16 + hi*4 + r]
    f32x4 s[2][4] = {};
#pragma unroll
    for (int ks = 0; ks < 2; ++ks) {
#pragma unroll
      for (int kb = 0; kb < 4; ++kb) {
        s[0][kb] = __builtin_amdgcn_mfma_f32_16x16x32_bf16(kreg[ks * 4 + kb], aq[0][ks], s[0][kb], 0, 0, 0);
        s[1][kb] = __builtin_amdgcn_mfma_f32_16x16x32_bf16(kreg[ks * 4 + kb], aq[1][ks], s[1][kb], 0, 0, 0);
      }
    }
#pragma unroll
    for (int kb = 0; kb < 4; ++kb) {
      s[0][kb] = __builtin_amdgcn_mfma_f32_16x16x32_bf16(kreg[8 + kb], aq[0][2], s[0][kb], 0, 0, 0);
      s[1][kb] = __builtin_amdgcn_mfma_f32_16x16x32_bf16(kreg[8 + kb], aq[1][2], s[1][kb], 0, 0, 0);
    }

    // ---- prefetch next tile's K (latency hides under softmax+stage+barrier+PV) ----
    load_k(kt + 1 < NT ? kt + 1 : NT - 1, kreg);

    // ---- fixed-shift softmax (raw v_exp); cvt_pk packs P pairs into pa words ----
    bf16x8 pa[2][2];
#pragma unroll
    for (int qg = 0; qg < 2; ++qg) {
      float p[4][4];
      float l = 0.f;
#pragma unroll
      for (int kb = 0; kb < 4; ++kb)
#pragma unroll
        for (int r = 0; r < 4; ++r) {
          p[kb][r] = fexp2(fmaf(s[qg][kb][r], c2, -4.0f));
          l += p[kb][r];
        }
#pragma unroll
      for (int c = 0; c < 2; ++c) {
        u32x4 wpk;
        wpk[0] = cvt_pk_bf16(p[2 * c][0],     p[2 * c][1]);
        wpk[1] = cvt_pk_bf16(p[2 * c][2],     p[2 * c][3]);
        wpk[2] = cvt_pk_bf16(p[2 * c + 1][0], p[2 * c + 1][1]);
        wpk[3] = cvt_pk_bf16(p[2 * c + 1][2], p[2 * c + 1][3]);
        pa[qg][c] = __builtin_bit_cast(bf16x8, wpk);
      }
      l += __shfl_xor(l, 16);
      l += __shfl_xor(l, 32);
      lacc[qg] += l;
    }

    // ---- stage next V tile (different buffer; 3-buf ring makes this race-free) ----
    if (kt < NT - 1) stage_v(kt + 1);

    __syncthreads();  // Vt[kt%3] visible (staged last iter)

    // ---- O += P V : B-frag rows permuted to match pa's kv order ----
    const bf16* vb = Vt + (kt % 3) * VTSTRIDE;
#pragma unroll
    for (int ks = 0; ks < 2; ++ks) {
#pragma unroll
      for (int n = 0; n < 5; ++n) {
        const int vrow = n * 16 + row15;
        const int rot = (vrow >> 3) << 3;
        const int cA = (ks * 32 + (hi << 2) + rot) & 63;
        const int cB = (ks * 32 + 16 + (hi << 2) + rot) & 63;
        bf16x4 loh = *reinterpret_cast<const bf16x4*>(vb + vrow * 72 + cA);
        bf16x4 hih = *reinterpret_cast<const bf16x4*>(vb + vrow * 72 + cB);
        bf16x8 bv = __builtin_shufflevector(loh, hih, 0, 1, 2, 3, 4, 5, 6, 7);
        oacc[0][n] = __builtin_amdgcn_mfma_f32_16x16x32_bf16(pa[0][ks], bv, oacc[0][n], 0, 0, 0);
        oacc[1][n] = __builtin_amdgcn_mfma_f32_16x16x32_bf16(pa[1][ks], bv, oacc[1][n], 0, 0, 0);
      }
    }
  }

  // ---- epilogue: broadcast l to D-layout rows, normalize, store ----
#pragma unroll
  for (int m = 0; m < 2; ++m) {
#pragma unroll
    for (int r = 0; r < 4; ++r) {
      float l = __shfl(lacc[m], hi * 4 + r);   // lane hi*4+r holds q=(hi*4+r)'s sum
      float inv = 1.0f / l;
#pragma unroll
      for (int n = 0; n < 5; ++n) {
        const int d = n * 16 + row15;
        if (d < HD) {
          const int row = q0 + w * 32 + m * 16 + hi * 4 + r;
          ctx[(size_t)row * ED + head * HD + d] = __float2bfloat16(oacc[m][n][r] * inv);
        }
      }
    }
  }
}

// ---------------- launch ----------------
extern "C" void kernel_launch(void* const* d_in, const int* in_sizes, int n_in,
                              void* d_out, int out_size, void* d_ws, size_t ws_size,
                              hipStream_t stream) {
  const float* hidden = (const float*)d_in[0];
  const float* qkv_w  = (const float*)d_in[1];
  const float* qkv_b  = (const float*)d_in[2];
  const float* out_w  = (const float*)d_in[3];
  const float* out_b  = (const float*)d_in[4];
  const float* rope   = (const float*)d_in[5];

  const size_t SZ_QKV = (size_t)SEQ * QKVN * 2;
  const size_t SZ_X   = (size_t)SEQ * ED * 2;
  const size_t SZ_W   = (size_t)QKVN * ED * 2;
  const size_t NEED   = SZ_QKV + SZ_X + SZ_W;
  if (ws_size < NEED) return;

  char* ws = (char*)d_ws;
  bf16* qkvbf = (bf16*)(ws);
  bf16* Xbf   = (bf16*)(ws + SZ_QKV);
  bf16* Wbf   = (bf16*)(ws + SZ_QKV + SZ_X);

  cvt_f32_bf16<<<(SEQ * ED / 4 + 255) / 256, 256, 0, stream>>>(hidden, Xbf, SEQ * ED / 4);
  cvt_f32_bf16<<<(QKVN * ED / 4 + 255) / 256, 256, 0, stream>>>(qkv_w, Wbf, QKVN * ED / 4);

  gemm_bt<<<(SEQ / 128) * (QKVN / 128), 256, 0, stream>>>(Xbf, Wbf, qkv_b, qkvbf,
                                                          SEQ, QKVN, ED, 1);

  cvt_f32_bf16<<<(ED * ED / 4 + 255) / 256, 256, 0, stream>>>(out_w, Wbf, ED * ED / 4);

  rope_inplace<<<SEQ, 256, 0, stream>>>(qkvbf, rope);

  attn<<<NSEG * NH * (SEGLEN / 128), 256, 0, stream>>>(qkvbf, Xbf);

  gemm_bt<<<(SEQ / 128) * (ED / 128), 256, 0, stream>>>(Xbf, Wbf, out_b, d_out,
                                                        SEQ, ED, ED, 0);
}

// Round 13
// 838.983 us; speedup vs baseline: 1.1527x; 1.1527x over previous
//
#include <hip/hip_runtime.h>
#include <hip/hip_bf16.h>
#include <cstdint>

#define SEQ   16384
#define ED    1152
#define NH    16
#define HD    72
#define NSEG  8
#define SEGLEN 2048
#define QKVN  3456
#define NT    (SEGLEN / 64)

typedef __bf16 bf16x8 __attribute__((ext_vector_type(8)));
typedef __bf16 bf16x4 __attribute__((ext_vector_type(4)));
typedef float  f32x4  __attribute__((ext_vector_type(4)));
typedef unsigned int u32x4 __attribute__((ext_vector_type(4)));
typedef __hip_bfloat16 bf16;

__device__ __forceinline__ unsigned short f2bfbits(float f) {
  bf16 h = __float2bfloat16(f);
  return __builtin_bit_cast(unsigned short, h);
}

__device__ __forceinline__ float fexp2(float x) {
#if __has_builtin(__builtin_amdgcn_exp2f)
  return __builtin_amdgcn_exp2f(x);
#else
  return exp2f(x);
#endif
}

// HW packed f32->bf16 convert (RNE); no builtin on gfx950 -> inline asm
__device__ __forceinline__ unsigned int cvt_pk_bf16(float lo, float hi) {
  unsigned int r;
  asm("v_cvt_pk_bf16_f32 %0, %1, %2" : "=v"(r) : "v"(lo), "v"(hi));
  return r;
}

__device__ __forceinline__ void gload_lds16(const void* g, void* l) {
  __builtin_amdgcn_global_load_lds(
      (__attribute__((address_space(1))) void*)(void*)g,
      (__attribute__((address_space(3))) void*)l, 16, 0, 0);
}

// ---------------- prep kernels ----------------
__global__ __launch_bounds__(256) void cvt_f32_bf16(const float* __restrict__ in,
                                                    bf16* __restrict__ out, int n4) {
  int i = blockIdx.x * 256 + threadIdx.x;
  if (i >= n4) return;
  float4 v = reinterpret_cast<const float4*>(in)[i];
  ushort4 o;
  o.x = f2bfbits(v.x); o.y = f2bfbits(v.y); o.z = f2bfbits(v.z); o.w = f2bfbits(v.w);
  reinterpret_cast<ushort4*>(out)[i] = o;
}

// ---------------- GEMM: C[M][N] = A[M][K] * B[N][K]^T + bias, m97-style ----------------
__global__ __launch_bounds__(256) void gemm_bt(const bf16* __restrict__ A,
                                               const bf16* __restrict__ B,
                                               const float* __restrict__ bias,
                                               void* __restrict__ Cout,
                                               int M, int N, int K, int out_bf16) {
  __shared__ __align__(16) bf16 As[128 * 32];
  __shared__ __align__(16) bf16 Bs[128 * 32];
  const int nt   = N >> 7;
  const int bm   = blockIdx.x / nt;
  const int bn   = blockIdx.x % nt;
  const int tid  = threadIdx.x;
  const int lane = tid & 63;
  const int wave = tid >> 6;
  const int wr   = wave >> 1, wc = wave & 1;

  const bf16* Ab = A + (size_t)(bm * 128) * K;
  const bf16* Bb = B + (size_t)(bn * 128) * K;
  const int r0 = tid >> 2;
  const int c0 = (tid & 3) << 3;

  char* AsB = (char*)As;
  char* BsB = (char*)Bs;
  const int ldsoff = wave * 1024;

  const int row15 = lane & 15;
  const int koff  = (lane >> 4) << 3;

  f32x4 acc[4][4] = {};

  for (int k0 = 0; k0 < K; k0 += 32) {
    gload_lds16(Ab + (size_t)r0 * K + k0 + c0,        AsB + ldsoff);
    gload_lds16(Ab + (size_t)(r0 + 64) * K + k0 + c0, AsB + 4096 + ldsoff);
    gload_lds16(Bb + (size_t)r0 * K + k0 + c0,        BsB + ldsoff);
    gload_lds16(Bb + (size_t)(r0 + 64) * K + k0 + c0, BsB + 4096 + ldsoff);
    __syncthreads();
    bf16x8 a[4], b[4];
#pragma unroll
    for (int mi = 0; mi < 4; ++mi)
      a[mi] = *reinterpret_cast<const bf16x8*>(&As[(wr * 64 + mi * 16 + row15) * 32 + koff]);
#pragma unroll
    for (int ni = 0; ni < 4; ++ni)
      b[ni] = *reinterpret_cast<const bf16x8*>(&Bs[(wc * 64 + ni * 16 + row15) * 32 + koff]);
#pragma unroll
    for (int mi = 0; mi < 4; ++mi)
#pragma unroll
      for (int ni = 0; ni < 4; ++ni)
        acc[mi][ni] = __builtin_amdgcn_mfma_f32_16x16x32_bf16(a[mi], b[ni], acc[mi][ni], 0, 0, 0);
    __syncthreads();
  }

  const int crow = bm * 128 + wr * 64 + (lane >> 4) * 4;
  const int ccol = bn * 128 + wc * 64 + row15;
#pragma unroll
  for (int mi = 0; mi < 4; ++mi)
#pragma unroll
    for (int ni = 0; ni < 4; ++ni) {
      const int col = ccol + ni * 16;
      const float bv = bias[col];
#pragma unroll
      for (int r = 0; r < 4; ++r) {
        const int row = crow + mi * 16 + r;
        float v = acc[mi][ni][r] + bv;
        if (out_bf16)
          reinterpret_cast<bf16*>(Cout)[(size_t)row * N + col] = __float2bfloat16(v);
        else
          reinterpret_cast<float*>(Cout)[(size_t)row * N + col] = v;
      }
    }
}

// ---------------- RoPE in-place on qkv [s][3456] ----------------
__global__ __launch_bounds__(256) void rope_inplace(bf16* __restrict__ qkv,
                                                    const float* __restrict__ ang) {
  const int s = blockIdx.x;
  bf16* row = qkv + (size_t)s * QKVN;
  for (int i = threadIdx.x; i < 2 * NH * 36; i += 256) {
    int t   = i / (NH * 36);
    int rem = i - t * (NH * 36);
    int h   = rem / 36;
    int d2  = rem - h * 36;
    float a  = ang[s * 36 + d2];
    float cs = cosf(a), sn = sinf(a);
    bf16* p = row + t * ED + h * HD + d2;
    float x1 = __bfloat162float(p[0]);
    float x2 = __bfloat162float(p[36]);
    p[0]  = __float2bfloat16(x1 * cs - x2 * sn);
    p[36] = __float2bfloat16(x2 * cs + x1 * sn);
  }
}

// ---------------- flash attention v10 ----------------
// v8 base (swapped QK^T in-register P, rotated Vt ring, 1 barrier/tile, (256,3),
// cvt_pk softmax) + T14 async-STAGE split for V: global->reg loads issue at the TOP
// of each iteration (latency hides under QKT+softmax), reg->LDS writes stay late,
// just before the barrier. K-prefetch of R12 reverted (it spilled: +65MB scratch).
#define VTSTRIDE (80 * 72)
__global__ __launch_bounds__(256, 3) void attn(const bf16* __restrict__ qkv,
                                               bf16* __restrict__ ctx) {
  const int blk  = blockIdx.x;
  // swizzle: all 16 q-tiles of one (seg,head) land on one XCD for K/V L2 locality
  const int qt   = (blk >> 3) & 15;
  const int g    = (((blk >> 7) & 15) << 3) | (blk & 7);
  const int head = g & 15;
  const int seg  = g >> 4;
  const int q0   = seg * SEGLEN + qt * 128;

  const int tid = threadIdx.x, lane = tid & 63, w = tid >> 6;
  const int row15 = lane & 15, hi = lane >> 4, koff = hi << 3;

  __shared__ __align__(16) bf16 Vt[3 * VTSTRIDE];  // [d][kv] stride 72, chunk-rotated, 3 bufs

  const bf16* Qg = qkv + (size_t)q0 * QKVN + head * HD;
  const bf16* Kg = qkv + (size_t)(seg * SEGLEN) * QKVN + ED + head * HD;
  const bf16* Vg = qkv + (size_t)(seg * SEGLEN) * QKVN + 2 * ED + head * HD;

  // Q fragments (2 q-groups x 3 k-chunks; chunk 2 = cols 64..71, low lanes only)
  const bf16x8 zero8 = {};
  bf16x8 aq[2][3];
#pragma unroll
  for (int m = 0; m < 2; ++m) {
    const bf16* qrow = Qg + (size_t)(w * 32 + m * 16 + row15) * QKVN;
    aq[m][0] = *reinterpret_cast<const bf16x8*>(qrow + koff);
    aq[m][1] = *reinterpret_cast<const bf16x8*>(qrow + 32 + koff);
    aq[m][2] = (hi == 0) ? *reinterpret_cast<const bf16x8*>(qrow + 64) : zero8;
  }

  f32x4 oacc[2][5] = {};
  float lacc[2] = {0.f, 0.f};
  const float c2 = 0.11785113019775793f * 1.4426950408889634f;  // scale * log2(e)

  // V tile staging, split into issue-early loads and write-late LDS stores.
  // thread's chunks: c = tid, tid+256, tid+512 (<576); j = c/9, d0 = (c%9)*8
  auto vload = [&](int kt2, bf16x8 (&vr)[3]) {
    const bf16* src0 = Vg + (size_t)kt2 * 64 * QKVN;
#pragma unroll
    for (int i = 0; i < 3; ++i) {
      int c = tid + i * 256;
      if (c < 576) {
        int j = c / 9, m9 = c - j * 9;
        vr[i] = *reinterpret_cast<const bf16x8*>(src0 + (size_t)j * QKVN + m9 * 8);
      }
    }
  };
  auto vwrite = [&](int kt2, const bf16x8 (&vr)[3]) {
    bf16* dst = Vt + (kt2 % 3) * VTSTRIDE;
#pragma unroll
    for (int i = 0; i < 3; ++i) {
      int c = tid + i * 256;
      if (c < 576) {
        int j = c / 9, m9 = c - j * 9;
        int d0 = m9 << 3;
        int jj = (j + (m9 << 3)) & 63;
        const unsigned short* u = reinterpret_cast<const unsigned short*>(&vr[i]);
#pragma unroll
        for (int e = 0; e < 8; ++e)
          dst[(d0 + e) * 72 + jj] = __builtin_bit_cast(bf16, u[e]);
      }
    }
  };

  // prologue: stage V tile 0
  {
    bf16x8 vr0[3];
    vload(0, vr0);
    vwrite(0, vr0);
  }

  for (int kt = 0; kt < NT; ++kt) {
    // ---- issue next V tile's global loads EARLY (hide under QKT+softmax) ----
    bf16x8 vr[3];
    if (kt + 1 < NT) vload(kt + 1, vr);

    // ---- S^T = K Q^T (swapped operands; K direct from global) ----
    // s[qg][kb][r] = S[q = w*32+qg*16+row15][kv = kb*16 + hi*4 + r]
    f32x4 s[2][4] = {};
    const bf16* Kt = Kg + (size_t)kt * 64 * QKVN;
#pragma unroll
    for (int ks = 0; ks < 2; ++ks) {
#pragma unroll
      for (int kb = 0; kb < 4; ++kb) {
        bf16x8 bk = *reinterpret_cast<const bf16x8*>(Kt + (size_t)(kb * 16 + row15) * QKVN + ks * 32 + koff);
        s[0][kb] = __builtin_amdgcn_mfma_f32_16x16x32_bf16(bk, aq[0][ks], s[0][kb], 0, 0, 0);
        s[1][kb] = __builtin_amdgcn_mfma_f32_16x16x32_bf16(bk, aq[1][ks], s[1][kb], 0, 0, 0);
      }
    }
#pragma unroll
    for (int kb = 0; kb < 4; ++kb) {
      bf16x8 bk = (hi == 0) ? *reinterpret_cast<const bf16x8*>(Kt + (size_t)(kb * 16 + row15) * QKVN + 64) : zero8;
      s[0][kb] = __builtin_amdgcn_mfma_f32_16x16x32_bf16(bk, aq[0][2], s[0][kb], 0, 0, 0);
      s[1][kb] = __builtin_amdgcn_mfma_f32_16x16x32_bf16(bk, aq[1][2], s[1][kb], 0, 0, 0);
    }

    // ---- fixed-shift softmax (raw v_exp); cvt_pk packs P pairs into pa words ----
    bf16x8 pa[2][2];
#pragma unroll
    for (int qg = 0; qg < 2; ++qg) {
      float p[4][4];
      float l = 0.f;
#pragma unroll
      for (int kb = 0; kb < 4; ++kb)
#pragma unroll
        for (int r = 0; r < 4; ++r) {
          p[kb][r] = fexp2(fmaf(s[qg][kb][r], c2, -4.0f));
          l += p[kb][r];
        }
#pragma unroll
      for (int c = 0; c < 2; ++c) {
        u32x4 wpk;
        wpk[0] = cvt_pk_bf16(p[2 * c][0],     p[2 * c][1]);
        wpk[1] = cvt_pk_bf16(p[2 * c][2],     p[2 * c][3]);
        wpk[2] = cvt_pk_bf16(p[2 * c + 1][0], p[2 * c + 1][1]);
        wpk[3] = cvt_pk_bf16(p[2 * c + 1][2], p[2 * c + 1][3]);
        pa[qg][c] = __builtin_bit_cast(bf16x8, wpk);
      }
      l += __shfl_xor(l, 16);
      l += __shfl_xor(l, 32);
      lacc[qg] += l;
    }

    // ---- write V regs to LDS LATE (loads have drained under QKT+softmax) ----
    if (kt + 1 < NT) vwrite(kt + 1, vr);

    __syncthreads();  // Vt[kt%3] visible (staged last iter)

    // ---- O += P V : B-frag rows permuted to match pa's kv order ----
    const bf16* vb = Vt + (kt % 3) * VTSTRIDE;
#pragma unroll
    for (int ks = 0; ks < 2; ++ks) {
#pragma unroll
      for (int n = 0; n < 5; ++n) {
        const int vrow = n * 16 + row15;
        const int rot = (vrow >> 3) << 3;
        const int cA = (ks * 32 + (hi << 2) + rot) & 63;
        const int cB = (ks * 32 + 16 + (hi << 2) + rot) & 63;
        bf16x4 loh = *reinterpret_cast<const bf16x4*>(vb + vrow * 72 + cA);
        bf16x4 hih = *reinterpret_cast<const bf16x4*>(vb + vrow * 72 + cB);
        bf16x8 bv = __builtin_shufflevector(loh, hih, 0, 1, 2, 3, 4, 5, 6, 7);
        oacc[0][n] = __builtin_amdgcn_mfma_f32_16x16x32_bf16(pa[0][ks], bv, oacc[0][n], 0, 0, 0);
        oacc[1][n] = __builtin_amdgcn_mfma_f32_16x16x32_bf16(pa[1][ks], bv, oacc[1][n], 0, 0, 0);
      }
    }
  }

  // ---- epilogue: broadcast l to D-layout rows, normalize, store ----
#pragma unroll
  for (int m = 0; m < 2; ++m) {
#pragma unroll
    for (int r = 0; r < 4; ++r) {
      float l = __shfl(lacc[m], hi * 4 + r);   // lane hi*4+r holds q=(hi*4+r)'s sum
      float inv = 1.0f / l;
#pragma unroll
      for (int n = 0; n < 5; ++n) {
        const int d = n * 16 + row15;
        if (d < HD) {
          const int row = q0 + w * 32 + m * 16 + hi * 4 + r;
          ctx[(size_t)row * ED + head * HD + d] = __float2bfloat16(oacc[m][n][r] * inv);
        }
      }
    }
  }
}

// ---------------- launch ----------------
extern "C" void kernel_launch(void* const* d_in, const int* in_sizes, int n_in,
                              void* d_out, int out_size, void* d_ws, size_t ws_size,
                              hipStream_t stream) {
  const float* hidden = (const float*)d_in[0];
  const float* qkv_w  = (const float*)d_in[1];
  const float* qkv_b  = (const float*)d_in[2];
  const float* out_w  = (const float*)d_in[3];
  const float* out_b  = (const float*)d_in[4];
  const float* rope   = (const float*)d_in[5];

  const size_t SZ_QKV = (size_t)SEQ * QKVN * 2;
  const size_t SZ_X   = (size_t)SEQ * ED * 2;
  const size_t SZ_W   = (size_t)QKVN * ED * 2;
  const size_t NEED   = SZ_QKV + SZ_X + SZ_W;
  if (ws_size < NEED) return;

  char* ws = (char*)d_ws;
  bf16* qkvbf = (bf16*)(ws);
  bf16* Xbf   = (bf16*)(ws + SZ_QKV);
  bf16* Wbf   = (bf16*)(ws + SZ_QKV + SZ_X);

  cvt_f32_bf16<<<(SEQ * ED / 4 + 255) / 256, 256, 0, stream>>>(hidden, Xbf, SEQ * ED / 4);
  cvt_f32_bf16<<<(QKVN * ED / 4 + 255) / 256, 256, 0, stream>>>(qkv_w, Wbf, QKVN * ED / 4);

  gemm_bt<<<(SEQ / 128) * (QKVN / 128), 256, 0, stream>>>(Xbf, Wbf, qkv_b, qkvbf,
                                                          SEQ, QKVN, ED, 1);

  cvt_f32_bf16<<<(ED * ED / 4 + 255) / 256, 256, 0, stream>>>(out_w, Wbf, ED * ED / 4);

  rope_inplace<<<SEQ, 256, 0, stream>>>(qkvbf, rope);

  attn<<<NSEG * NH * (SEGLEN / 128), 256, 0, stream>>>(qkvbf, Xbf);

  gemm_bt<<<(SEQ / 128) * (ED / 128), 256, 0, stream>>>(Xbf, Wbf, out_b, d_out,
                                                        SEQ, ED, ED, 0);
}

// Round 14
// 787.182 us; speedup vs baseline: 1.2286x; 1.0658x over previous
//
#include <hip/hip_runtime.h>
#include <hip/hip_bf16.h>
#include <cstdint>

#define SEQ   16384
#define ED    1152
#define NH    16
#define HD    72
#define NSEG  8
#define SEGLEN 2048
#define QKVN  3456

typedef __bf16 bf16x8 __attribute__((ext_vector_type(8)));
typedef float  f32x4  __attribute__((ext_vector_type(4)));
typedef __hip_bfloat16 bf16;

__device__ __forceinline__ unsigned short f2bfbits(float f) {
  bf16 h = __float2bfloat16(f);
  return __builtin_bit_cast(unsigned short, h);
}

__device__ __forceinline__ float fexp2(float x) {
#if __has_builtin(__builtin_amdgcn_exp2f)
  return __builtin_amdgcn_exp2f(x);
#else
  return exp2f(x);
#endif
}

__device__ __forceinline__ void gload_lds16(const void* g, void* l) {
  __builtin_amdgcn_global_load_lds(
      (__attribute__((address_space(1))) void*)(void*)g,
      (__attribute__((address_space(3))) void*)l, 16, 0, 0);
}

// ---------------- prep kernels ----------------
__global__ __launch_bounds__(256) void cvt_f32_bf16(const float* __restrict__ in,
                                                    bf16* __restrict__ out, int n4) {
  int i = blockIdx.x * 256 + threadIdx.x;
  if (i >= n4) return;
  float4 v = reinterpret_cast<const float4*>(in)[i];
  ushort4 o;
  o.x = f2bfbits(v.x); o.y = f2bfbits(v.y); o.z = f2bfbits(v.z); o.w = f2bfbits(v.w);
  reinterpret_cast<ushort4*>(out)[i] = o;
}

// ---------------- GEMM: C[M][N] = A[M][K] * B[N][K]^T + bias, m97-style ----------------
__global__ __launch_bounds__(256) void gemm_bt(const bf16* __restrict__ A,
                                               const bf16* __restrict__ B,
                                               const float* __restrict__ bias,
                                               void* __restrict__ Cout,
                                               int M, int N, int K, int out_bf16) {
  __shared__ __align__(16) bf16 As[128 * 32];
  __shared__ __align__(16) bf16 Bs[128 * 32];
  const int nt   = N >> 7;
  const int bm   = blockIdx.x / nt;
  const int bn   = blockIdx.x % nt;
  const int tid  = threadIdx.x;
  const int lane = tid & 63;
  const int wave = tid >> 6;
  const int wr   = wave >> 1, wc = wave & 1;

  const bf16* Ab = A + (size_t)(bm * 128) * K;
  const bf16* Bb = B + (size_t)(bn * 128) * K;
  const int r0 = tid >> 2;
  const int c0 = (tid & 3) << 3;

  char* AsB = (char*)As;
  char* BsB = (char*)Bs;
  const int ldsoff = wave * 1024;

  const int row15 = lane & 15;
  const int koff  = (lane >> 4) << 3;

  f32x4 acc[4][4] = {};

  for (int k0 = 0; k0 < K; k0 += 32) {
    gload_lds16(Ab + (size_t)r0 * K + k0 + c0,        AsB + ldsoff);
    gload_lds16(Ab + (size_t)(r0 + 64) * K + k0 + c0, AsB + 4096 + ldsoff);
    gload_lds16(Bb + (size_t)r0 * K + k0 + c0,        BsB + ldsoff);
    gload_lds16(Bb + (size_t)(r0 + 64) * K + k0 + c0, BsB + 4096 + ldsoff);
    __syncthreads();
    bf16x8 a[4], b[4];
#pragma unroll
    for (int mi = 0; mi < 4; ++mi)
      a[mi] = *reinterpret_cast<const bf16x8*>(&As[(wr * 64 + mi * 16 + row15) * 32 + koff]);
#pragma unroll
    for (int ni = 0; ni < 4; ++ni)
      b[ni] = *reinterpret_cast<const bf16x8*>(&Bs[(wc * 64 + ni * 16 + row15) * 32 + koff]);
#pragma unroll
    for (int mi = 0; mi < 4; ++mi)
#pragma unroll
      for (int ni = 0; ni < 4; ++ni)
        acc[mi][ni] = __builtin_amdgcn_mfma_f32_16x16x32_bf16(a[mi], b[ni], acc[mi][ni], 0, 0, 0);
    __syncthreads();
  }

  const int crow = bm * 128 + wr * 64 + (lane >> 4) * 4;
  const int ccol = bn * 128 + wc * 64 + row15;
#pragma unroll
  for (int mi = 0; mi < 4; ++mi)
#pragma unroll
    for (int ni = 0; ni < 4; ++ni) {
      const int col = ccol + ni * 16;
      const float bv = bias[col];
#pragma unroll
      for (int r = 0; r < 4; ++r) {
        const int row = crow + mi * 16 + r;
        float v = acc[mi][ni][r] + bv;
        if (out_bf16)
          reinterpret_cast<bf16*>(Cout)[(size_t)row * N + col] = __float2bfloat16(v);
        else
          reinterpret_cast<float*>(Cout)[(size_t)row * N + col] = v;
      }
    }
}

// ---------------- RoPE in-place on qkv [s][3456] ----------------
__global__ __launch_bounds__(256) void rope_inplace(bf16* __restrict__ qkv,
                                                    const float* __restrict__ ang) {
  const int s = blockIdx.x;
  bf16* row = qkv + (size_t)s * QKVN;
  for (int i = threadIdx.x; i < 2 * NH * 36; i += 256) {
    int t   = i / (NH * 36);
    int rem = i - t * (NH * 36);
    int h   = rem / 36;
    int d2  = rem - h * 36;
    float a  = ang[s * 36 + d2];
    float cs = cosf(a), sn = sinf(a);
    bf16* p = row + t * ED + h * HD + d2;
    float x1 = __bfloat162float(p[0]);
    float x2 = __bfloat162float(p[36]);
    p[0]  = __float2bfloat16(x1 * cs - x2 * sn);
    p[36] = __float2bfloat16(x2 * cs + x1 * sn);
  }
}

// ---------------- flash attention v11 = R7's v4 (best measured: 476us) + 2 tweaks ----
// (1) raw v_exp_f32 for the 32 exp calls (R7 is VALU-bound at 41%)
// (2) s_setprio(1) around both MFMA clusters (T5; 4 indep blocks/CU -> m191 mechanism)
// Structure: 128-q-tile, 4 waves, LDS-P, rotated single-Vt + pipelined
// {bar; PV; bar; stageV || QKT || softmax}, __launch_bounds__(256,4).
__global__ __launch_bounds__(256, 4) void attn(const bf16* __restrict__ qkv,
                                               bf16* __restrict__ ctx) {
  const int blk  = blockIdx.x;
  // swizzle: all 16 q-tiles of one (seg,head) land on one XCD for K/V L2 locality
  const int qt   = (blk >> 3) & 15;
  const int g    = (((blk >> 7) & 15) << 3) | (blk & 7);
  const int head = g & 15;
  const int seg  = g >> 4;
  const int q0   = seg * SEGLEN + qt * 128;

  const int tid = threadIdx.x, lane = tid & 63, w = tid >> 6;
  const int row15 = lane & 15, hi = lane >> 4, koff = hi << 3;

  __shared__ __align__(16) bf16 Vt[80 * 72];   // [d][kv] stride 72, chunk-rotated; row 72 = ones
  __shared__ __align__(16) bf16 Ps[128 * 72];  // [q][kv] stride 72; per-wave exclusive rows

  const bf16* Qg = qkv + (size_t)q0 * QKVN + head * HD;
  const bf16* Kg = qkv + (size_t)(seg * SEGLEN) * QKVN + ED + head * HD;
  const bf16* Vg = qkv + (size_t)(seg * SEGLEN) * QKVN + 2 * ED + head * HD;

  // init pad rows 72..79 (row 72 = 1.0 row-sum column; constant rows are invariant
  // under the column rotation, so straight writes are fine)
  {
    const bf16 one  = __float2bfloat16(1.0f);
    const bf16 zerob = __float2bfloat16(0.0f);
    for (int e = tid; e < 8 * 72; e += 256)
      Vt[72 * 72 + e] = (e < 72) ? one : zerob;
  }

  // Q fragments in registers (2 m-frags x 3 k-chunks; chunk 2 = cols 64..71, low lanes only)
  const bf16x8 zero8 = {};
  bf16x8 aq[2][3];
#pragma unroll
  for (int m = 0; m < 2; ++m) {
    const bf16* qrow = Qg + (size_t)(w * 32 + m * 16 + row15) * QKVN;
    aq[m][0] = *reinterpret_cast<const bf16x8*>(qrow + koff);
    aq[m][1] = *reinterpret_cast<const bf16x8*>(qrow + 32 + koff);
    aq[m][2] = (hi == 0) ? *reinterpret_cast<const bf16x8*>(qrow + 64) : zero8;
  }

  f32x4 oacc[2][5] = {};
  const float c2 = 0.11785113019775793f * 1.4426950408889634f;  // scale * log2(e)

  // stage V tile kt2 into Vt with column rotation jj=(j+8*(d>>3))&63
  auto stage_v = [&](int kt2) {
    const bf16* src0 = Vg + (size_t)kt2 * 64 * QKVN;
    for (int c = tid; c < 576; c += 256) {
      int j = c / 9, m9 = c - j * 9;
      int d0 = m9 << 3;
      int jj = (j + (m9 << 3)) & 63;
      bf16x8 v = *reinterpret_cast<const bf16x8*>(src0 + (size_t)j * QKVN + d0);
      const unsigned short* u = reinterpret_cast<const unsigned short*>(&v);
#pragma unroll
      for (int e = 0; e < 8; ++e)
        Vt[(d0 + e) * 72 + jj] = __builtin_bit_cast(bf16, u[e]);
    }
  };

  // QK^T (K direct from global) + fixed-shift softmax + u16 P-stores
  auto qkt_soft = [&](int kt2) {
    f32x4 s[2][4] = {};
    const bf16* Kt = Kg + (size_t)kt2 * 64 * QKVN;
    __builtin_amdgcn_s_setprio(1);
#pragma unroll
    for (int ks = 0; ks < 2; ++ks) {
#pragma unroll
      for (int n = 0; n < 4; ++n) {
        bf16x8 bk = *reinterpret_cast<const bf16x8*>(Kt + (size_t)(n * 16 + row15) * QKVN + ks * 32 + koff);
        s[0][n] = __builtin_amdgcn_mfma_f32_16x16x32_bf16(aq[0][ks], bk, s[0][n], 0, 0, 0);
        s[1][n] = __builtin_amdgcn_mfma_f32_16x16x32_bf16(aq[1][ks], bk, s[1][n], 0, 0, 0);
      }
    }
#pragma unroll
    for (int n = 0; n < 4; ++n) {
      bf16x8 bk = (hi == 0) ? *reinterpret_cast<const bf16x8*>(Kt + (size_t)(n * 16 + row15) * QKVN + 64) : zero8;
      s[0][n] = __builtin_amdgcn_mfma_f32_16x16x32_bf16(aq[0][2], bk, s[0][n], 0, 0, 0);
      s[1][n] = __builtin_amdgcn_mfma_f32_16x16x32_bf16(aq[1][2], bk, s[1][n], 0, 0, 0);
    }
    __builtin_amdgcn_s_setprio(0);
    const int prow_base = w * 32 + hi * 4;
#pragma unroll
    for (int m = 0; m < 2; ++m)
#pragma unroll
      for (int n = 0; n < 4; ++n)
#pragma unroll
        for (int r = 0; r < 4; ++r) {
          float p = fexp2(fmaf(s[m][n][r], c2, -4.0f));
          Ps[(prow_base + m * 16 + r) * 72 + n * 16 + row15] =
              __builtin_bit_cast(bf16, f2bfbits(p));
        }
  };

  auto pv = [&]() {
    __builtin_amdgcn_s_setprio(1);
#pragma unroll
    for (int ks = 0; ks < 2; ++ks) {
      bf16x8 ap0 = *reinterpret_cast<const bf16x8*>(&Ps[(w * 32 + row15) * 72 + ks * 32 + koff]);
      bf16x8 ap1 = *reinterpret_cast<const bf16x8*>(&Ps[(w * 32 + 16 + row15) * 72 + ks * 32 + koff]);
#pragma unroll
      for (int n = 0; n < 5; ++n) {
        const int vrow = n * 16 + row15;
        const int col = (ks * 32 + (hi << 3) + ((vrow >> 3) << 3)) & 63;
        bf16x8 bv = *reinterpret_cast<const bf16x8*>(&Vt[vrow * 72 + col]);
        oacc[0][n] = __builtin_amdgcn_mfma_f32_16x16x32_bf16(ap0, bv, oacc[0][n], 0, 0, 0);
        oacc[1][n] = __builtin_amdgcn_mfma_f32_16x16x32_bf16(ap1, bv, oacc[1][n], 0, 0, 0);
      }
    }
    __builtin_amdgcn_s_setprio(0);
  };

  // pipelined main loop: stage/QKT/softmax of kt+1 overlap the barrier shadow of PV(kt)
  stage_v(0);
  qkt_soft(0);
  for (int kt = 0; kt < SEGLEN / 64; ++kt) {
    __syncthreads();   // Ps(kt) + Vt(kt) visible to all waves
    pv();
    __syncthreads();   // Vt/Ps consumed; safe to overwrite
    if (kt < SEGLEN / 64 - 1) {
      stage_v(kt + 1);
      qkt_soft(kt + 1);
    }
  }

  // ---- epilogue: l = oacc[m][4] at row15==8; normalize & store ----
#pragma unroll
  for (int m = 0; m < 2; ++m) {
#pragma unroll
    for (int r = 0; r < 4; ++r) {
      float l = __shfl(oacc[m][4][r], (lane & 48) + 8);
      float inv = 1.0f / l;
#pragma unroll
      for (int n = 0; n < 5; ++n) {
        const int d = n * 16 + row15;
        if (d < HD) {
          const int row = q0 + w * 32 + m * 16 + hi * 4 + r;
          ctx[(size_t)row * ED + head * HD + d] = __float2bfloat16(oacc[m][n][r] * inv);
        }
      }
    }
  }
}

// ---------------- launch ----------------
extern "C" void kernel_launch(void* const* d_in, const int* in_sizes, int n_in,
                              void* d_out, int out_size, void* d_ws, size_t ws_size,
                              hipStream_t stream) {
  const float* hidden = (const float*)d_in[0];
  const float* qkv_w  = (const float*)d_in[1];
  const float* qkv_b  = (const float*)d_in[2];
  const float* out_w  = (const float*)d_in[3];
  const float* out_b  = (const float*)d_in[4];
  const float* rope   = (const float*)d_in[5];

  const size_t SZ_QKV = (size_t)SEQ * QKVN * 2;
  const size_t SZ_X   = (size_t)SEQ * ED * 2;
  const size_t SZ_W   = (size_t)QKVN * ED * 2;
  const size_t NEED   = SZ_QKV + SZ_X + SZ_W;
  if (ws_size < NEED) return;

  char* ws = (char*)d_ws;
  bf16* qkvbf = (bf16*)(ws);
  bf16* Xbf   = (bf16*)(ws + SZ_QKV);
  bf16* Wbf   = (bf16*)(ws + SZ_QKV + SZ_X);

  cvt_f32_bf16<<<(SEQ * ED / 4 + 255) / 256, 256, 0, stream>>>(hidden, Xbf, SEQ * ED / 4);
  cvt_f32_bf16<<<(QKVN * ED / 4 + 255) / 256, 256, 0, stream>>>(qkv_w, Wbf, QKVN * ED / 4);

  gemm_bt<<<(SEQ / 128) * (QKVN / 128), 256, 0, stream>>>(Xbf, Wbf, qkv_b, qkvbf,
                                                          SEQ, QKVN, ED, 1);

  cvt_f32_bf16<<<(ED * ED / 4 + 255) / 256, 256, 0, stream>>>(out_w, Wbf, ED * ED / 4);

  rope_inplace<<<SEQ, 256, 0, stream>>>(qkvbf, rope);

  attn<<<NSEG * NH * (SEGLEN / 128), 256, 0, stream>>>(qkvbf, Xbf);

  gemm_bt<<<(SEQ / 128) * (ED / 128), 256, 0, stream>>>(Xbf, Wbf, out_b, d_out,
                                                        SEQ, ED, ED, 0);
}